// Round 4
// baseline (234.094 us; speedup 1.0000x reference)
//
#include <hip/hip_runtime.h>
#include <math.h>

// PCEN: out = (x / (smooth + eps)^alpha + delta)^r - delta^r
// smooth[0]=x[0]; smooth[t] = 0.975*smooth[t-1] + 0.025*x[t]
// x: [64,128,4096] fp32 -> 8192 independent rows of T=4096.
//
// One WAVE per row (no __syncthreads, no LDS arrays). Row processed in 16
// chunks of 256 floats; each lane owns 4 contiguous elements (float4 load =
// perfectly coalesced 1KB per wave instr), rolling 8-deep prefetch.
//
// Scan trick: every lane's 4-elem segment has the SAME decay A = 0.975^4,
// so the affine-pair scan collapses to a scan over B alone with
// compile-time constant multipliers 0.975^(4*off). Chunk carry propagates
// with constant 0.975^256. The t=0 absorbing map (smooth[0]=x[0]) is exact:
// lane 0's A never enters any other lane's B-composition.

#define T_LEN 4096
#define BLOCK 256          // 4 waves per block
#define WPB   (BLOCK / 64)
#define CHUNK 256          // floats per chunk (64 lanes x 4)
#define NCHUNK (T_LEN / CHUNK)   // 16

__global__ __launch_bounds__(BLOCK) void pcen_kernel(const float* __restrict__ x,
                                                     float* __restrict__ out) {
    constexpr float AC  = 0.975f;            // decay
    constexpr float SC  = 0.025f;            // gain
    constexpr float ALPHA = 0.98f;
    constexpr float EPS   = 1e-6f;
    constexpr float DELTA = 2.0f;
    constexpr float SQRT_DELTA = 1.4142135623730951f;
    // 0.975^(4*off) scan constants
    constexpr float C1  = 0.903687890625f;   // 0.975^4
    constexpr float C2  = 0.8166517927f;     // 0.975^8
    constexpr float C4  = 0.6669201600f;     // 0.975^16
    constexpr float C8  = 0.4447824950f;     // 0.975^32
    constexpr float C16 = 0.1978314646f;     // 0.975^64
    constexpr float C32 = 0.0391372884f;     // 0.975^128
    constexpr float A_CHUNK = 0.0015317273f; // 0.975^256
    constexpr float L2A4 = -0.14610666f;     // 4*log2(0.975)

    const int lane = threadIdx.x & 63;
    const int row  = blockIdx.x * WPB + (threadIdx.x >> 6);

    const float* __restrict__ xr  = x   + (size_t)row * T_LEN;
    float* __restrict__       orr = out + (size_t)row * T_LEN;
    const int loff = lane * 4;

    // per-lane constant: 0.975^(4*lane)  (lane 0 -> 1.0)
    const float a4L = __builtin_amdgcn_exp2f(L2A4 * (float)lane);

    // rolling prefetch, depth 8
    float4 d[8];
#pragma unroll
    for (int c = 0; c < 8; ++c)
        d[c] = *(const float4*)(xr + c * CHUNK + loff);

    float yc = 0.0f;   // smooth value at end of previous chunk

#pragma unroll
    for (int c = 0; c < NCHUNK; ++c) {
        float4 v = d[c & 7];
        if (c + 8 < NCHUNK)
            d[c & 7] = *(const float4*)(xr + (c + 8) * CHUNK + loff);

        const bool first = (c == 0) && (lane == 0);   // global t==0

        // local compose over 4 elements -> B (A is the constant 0.975^4,
        // except the absorbing t==0 map which has A=0)
        float B = first ? v.x : SC * v.x;
        B = fmaf(AC, B, SC * v.y);
        B = fmaf(AC, B, SC * v.z);
        B = fmaf(AC, B, SC * v.w);

        // constant-coefficient inclusive scan of B across the wave
        float Bu;
        Bu = __shfl_up(B, 1);  if (lane >= 1)  B = fmaf(C1,  Bu, B);
        Bu = __shfl_up(B, 2);  if (lane >= 2)  B = fmaf(C2,  Bu, B);
        Bu = __shfl_up(B, 4);  if (lane >= 4)  B = fmaf(C4,  Bu, B);
        Bu = __shfl_up(B, 8);  if (lane >= 8)  B = fmaf(C8,  Bu, B);
        Bu = __shfl_up(B, 16); if (lane >= 16) B = fmaf(C16, Bu, B);
        Bu = __shfl_up(B, 32); if (lane >= 32) B = fmaf(C32, Bu, B);

        // exclusive prefix + carry-in: smooth entering this lane's segment
        float exB = __shfl_up(B, 1);
        if (lane == 0) exB = 0.0f;
        float y = fmaf(a4L, yc, exB);

        // chunk carry for next iteration (exact: for c==0, yc was 0)
        float Btot = __shfl(B, 63);
        yc = fmaf(A_CHUNK, yc, Btot);

        // replay 4 elements + pointwise PCEN
        float4 o;
        {
            y = first ? v.x : fmaf(AC, y, SC * v.x);
            float p = __builtin_amdgcn_exp2f(-ALPHA * __builtin_amdgcn_logf(y + EPS));
            o.x = __builtin_amdgcn_sqrtf(fmaf(v.x, p, DELTA)) - SQRT_DELTA;
        }
        {
            y = fmaf(AC, y, SC * v.y);
            float p = __builtin_amdgcn_exp2f(-ALPHA * __builtin_amdgcn_logf(y + EPS));
            o.y = __builtin_amdgcn_sqrtf(fmaf(v.y, p, DELTA)) - SQRT_DELTA;
        }
        {
            y = fmaf(AC, y, SC * v.z);
            float p = __builtin_amdgcn_exp2f(-ALPHA * __builtin_amdgcn_logf(y + EPS));
            o.z = __builtin_amdgcn_sqrtf(fmaf(v.z, p, DELTA)) - SQRT_DELTA;
        }
        {
            y = fmaf(AC, y, SC * v.w);
            float p = __builtin_amdgcn_exp2f(-ALPHA * __builtin_amdgcn_logf(y + EPS));
            o.w = __builtin_amdgcn_sqrtf(fmaf(v.w, p, DELTA)) - SQRT_DELTA;
        }

        *(float4*)(orr + c * CHUNK + loff) = o;
    }
}

extern "C" void kernel_launch(void* const* d_in, const int* in_sizes, int n_in,
                              void* d_out, int out_size, void* d_ws, size_t ws_size,
                              hipStream_t stream) {
    const float* x = (const float*)d_in[0];
    float* out = (float*)d_out;
    const int rows = in_sizes[0] / T_LEN;      // 8192
    pcen_kernel<<<rows / WPB, BLOCK, 0, stream>>>(x, out);
}